// Round 5
// baseline (305.866 us; speedup 1.0000x reference)
//
#include <hip/hip_runtime.h>

#define N_NODES 100000
#define DIM     128
#define NEDGE   640000
#define BN_EPS  1e-5f
#define NB_SCAN 98      // ceil(100000/1024)

// k_prep block ranges
#define PB_X    6250    // 12.8M elems / (256 thr * 8)
#define PB_W    64      // 16384 / 256
#define PB_CNT  2500    // 640000 / 256

#define NBUCKET 64
#define GBLK    391     // ceil(100000 / 256) -- 256 rows per gemm block

typedef __bf16 bf16x8 __attribute__((ext_vector_type(8)));
typedef float  f32x4  __attribute__((ext_vector_type(4)));
typedef unsigned short u16x8 __attribute__((ext_vector_type(8)));

__device__ __forceinline__ unsigned short f2b(float f) {
    unsigned u = __builtin_bit_cast(unsigned, f);
    u += 0x7fffu + ((u >> 16) & 1u);            // RNE
    return (unsigned short)(u >> 16);
}
__device__ __forceinline__ float b2f(unsigned short b) {
    return __builtin_bit_cast(float, ((unsigned)b) << 16);
}

// ===========================================================================
// Fused prep: x->bf16, W1/W2 transpose->bf16, degree count.
// ===========================================================================
__global__ __launch_bounds__(256) void k_prep(const float* __restrict__ x,
                                              const float* __restrict__ W1,
                                              const float* __restrict__ W2,
                                              const int* __restrict__ ei,
                                              unsigned short* __restrict__ xb,
                                              unsigned short* __restrict__ Wt1,
                                              unsigned short* __restrict__ Wt2,
                                              int* __restrict__ rowptr) {
    const int b = blockIdx.x;
    const int t = threadIdx.x;
    if (b < PB_X) {
        size_t base = ((size_t)b * 256 + t) * 8;
        float4 v0 = *(const float4*)(x + base);
        float4 v1 = *(const float4*)(x + base + 4);
        u16x8 o;
        o[0] = f2b(v0.x); o[1] = f2b(v0.y); o[2] = f2b(v0.z); o[3] = f2b(v0.w);
        o[4] = f2b(v1.x); o[5] = f2b(v1.y); o[6] = f2b(v1.z); o[7] = f2b(v1.w);
        *(u16x8*)(xb + base) = o;
    } else if (b < PB_X + PB_W) {
        int idx = (b - PB_X) * 256 + t;
        int k = idx >> 7, n = idx & 127;
        Wt1[n * 128 + k] = f2b(W1[idx]);
    } else if (b < PB_X + 2 * PB_W) {
        int idx = (b - PB_X - PB_W) * 256 + t;
        int k = idx >> 7, n = idx & 127;
        Wt2[n * 128 + k] = f2b(W2[idx]);
    } else {
        int e = (b - PB_X - 2 * PB_W) * 256 + t;
        if (e < NEDGE) atomicAdd(&rowptr[ei[NEDGE + e]], 1);
    }
}

// ===========================================================================
// CSR scan + fill
// ===========================================================================
__global__ __launch_bounds__(256) void k_scan1(int* __restrict__ rowptr,
                                               int* __restrict__ bsum) {
    __shared__ int tsum[256];
    const int t = threadIdx.x;
    const int base = blockIdx.x * 1024 + t * 4;
    int v[4];
    #pragma unroll
    for (int j = 0; j < 4; ++j)
        v[j] = (base + j < N_NODES) ? rowptr[base + j] : 0;
    int s = v[0] + v[1] + v[2] + v[3];
    tsum[t] = s;
    __syncthreads();
    #pragma unroll
    for (int off = 1; off < 256; off <<= 1) {
        int a = tsum[t];
        int b = (t >= off) ? tsum[t - off] : 0;
        __syncthreads();
        tsum[t] = a + b;
        __syncthreads();
    }
    int run = tsum[t] - s;
    #pragma unroll
    for (int j = 0; j < 4; ++j) {
        int nv = run;
        run += v[j];
        if (base + j < N_NODES) rowptr[base + j] = nv;
    }
    if (t == 255) bsum[blockIdx.x] = tsum[255];
}

__global__ __launch_bounds__(128) void k_scan_mid(int* __restrict__ bsum) {
    __shared__ int sh[128];
    const int t = threadIdx.x;
    int orig = (t < NB_SCAN) ? bsum[t] : 0;
    sh[t] = orig;
    __syncthreads();
    #pragma unroll
    for (int off = 1; off < 128; off <<= 1) {
        int a = sh[t];
        int b = (t >= off) ? sh[t - off] : 0;
        __syncthreads();
        sh[t] = a + b;
        __syncthreads();
    }
    if (t < NB_SCAN) bsum[t] = sh[t] - orig;
}

__global__ __launch_bounds__(256) void k_scan_add(int* __restrict__ rowptr,
                                                  const int* __restrict__ bsum,
                                                  int* __restrict__ cursor) {
    const int t = threadIdx.x;
    const int base = blockIdx.x * 1024 + t * 4;
    const int add = bsum[blockIdx.x];
    #pragma unroll
    for (int j = 0; j < 4; ++j) {
        if (base + j < N_NODES) {
            int r = rowptr[base + j] + add;
            rowptr[base + j] = r;
            cursor[base + j] = r;
        }
    }
    if (blockIdx.x == 0 && t == 0) rowptr[N_NODES] = NEDGE;
}

__global__ __launch_bounds__(256) void k_fill(const int* __restrict__ ei,
                                              int* __restrict__ cursor,
                                              int* __restrict__ srcidx) {
    int e = blockIdx.x * 256 + threadIdx.x;
    if (e < NEDGE) {
        int dst = ei[NEDGE + e];
        int pos = atomicAdd(&cursor[dst], 1);
        srcidx[pos] = ei[e];
    }
}

// ===========================================================================
// Pull aggregation (bf16 gather, 4 edges per load instruction).
// ===========================================================================
__global__ __launch_bounds__(256) void k_aggregate(const unsigned short* __restrict__ xb,
                                                   const int* __restrict__ rowptr,
                                                   const int* __restrict__ srcidx,
                                                   const float* __restrict__ epsp,
                                                   unsigned short* __restrict__ Ab) {
    const int wid  = (blockIdx.x * 256 + threadIdx.x) >> 6;
    const int lane = threadIdx.x & 63;
    if (wid >= N_NODES) return;
    const int g = lane >> 4;        // edge group 0..3
    const int c = (lane & 15) * 8;  // col offset
    const float scale = 1.0f + epsp[0];
    const int beg = rowptr[wid];
    const int end = rowptr[wid + 1];

    float acc[8] = {0.f, 0.f, 0.f, 0.f, 0.f, 0.f, 0.f, 0.f};
    for (int p = beg; p < end; p += 4) {
        int e = p + g;
        if (e < end) {
            int s = srcidx[e];
            u16x8 v = *(const u16x8*)(xb + (size_t)s * 128 + c);
            #pragma unroll
            for (int j = 0; j < 8; ++j) acc[j] += b2f(v[j]);
        }
    }
    if (g == 0) {
        u16x8 v = *(const u16x8*)(xb + (size_t)wid * 128 + c);
        #pragma unroll
        for (int j = 0; j < 8; ++j) acc[j] = fmaf(scale, b2f(v[j]), acc[j]);
    }
    #pragma unroll
    for (int j = 0; j < 8; ++j) acc[j] += __shfl_down(acc[j], 32);
    #pragma unroll
    for (int j = 0; j < 8; ++j) acc[j] += __shfl_down(acc[j], 16);
    if (lane < 16) {
        u16x8 o;
        #pragma unroll
        for (int j = 0; j < 8; ++j) o[j] = f2b(acc[j]);
        *(u16x8*)(Ab + (size_t)wid * 128 + c) = o;
    }
}

// ===========================================================================
// GEMM1 (MFMA bf16): h = A @ W1 + b1 (bf16, in-place over A) + bucketed stats.
// 4 waves/block, 4 M-tiles (16 rows) per wave, B-frags straight from global
// (L2-resident Wt), 2-tile-deep A prefetch, per-wave LDS epilogue staging.
// ===========================================================================
__global__ __launch_bounds__(256) void k_gemm1(unsigned short* __restrict__ Ab,
                                               const unsigned short* __restrict__ Wt,
                                               const float* __restrict__ b1,
                                               float* __restrict__ buckets) {
    __shared__ __align__(16) unsigned short stage[4][2048];   // 4 KB per wave
    __shared__ float sl[256];
    const int t = threadIdx.x;
    const int w = t >> 6;
    const int lane = t & 63;
    const int n15 = lane & 15;
    const int quad = lane >> 4;
    const int koff = quad * 8;
    sl[t] = 0.f;

    const int base_row = blockIdx.x * 256 + w * 64;
    const unsigned short* bp0 = Wt + n15 * 128 + koff;

    // 2-tile-deep A prefetch
    int4 Afr[2][4];
    #pragma unroll
    for (int sl0 = 0; sl0 < 2; ++sl0) {
        int r0 = base_row + sl0 * 16;
        if (r0 < N_NODES) {
            const unsigned short* ap = Ab + (size_t)(r0 + n15) * 128 + koff;
            #pragma unroll
            for (int ks = 0; ks < 4; ++ks)
                Afr[sl0][ks] = *(const int4*)(ap + ks * 32);
        }
    }
    __syncthreads();   // sl init visible to all waves

    float s[8] = {0.f, 0.f, 0.f, 0.f, 0.f, 0.f, 0.f, 0.f};
    float q[8] = {0.f, 0.f, 0.f, 0.f, 0.f, 0.f, 0.f, 0.f};

    #pragma unroll
    for (int ti = 0; ti < 4; ++ti) {
        const int row0 = base_row + ti * 16;
        const bool valid = row0 < N_NODES;
        const int slot = ti & 1;
        f32x4 acc[8] = {};
        if (valid) {
            #pragma unroll
            for (int ks = 0; ks < 4; ++ks) {
                bf16x8 af = __builtin_bit_cast(bf16x8, Afr[slot][ks]);
                const unsigned short* bp = bp0 + ks * 32;
                #pragma unroll
                for (int c = 0; c < 8; ++c) {
                    int4 braw = *(const int4*)(bp + c * 2048);
                    acc[c] = __builtin_amdgcn_mfma_f32_16x16x32_bf16(
                        af, __builtin_bit_cast(bf16x8, braw), acc[c], 0, 0, 0);
                }
            }
        }
        if (ti < 2) {   // prefetch tile ti+2 into this slot
            int r2 = base_row + (ti + 2) * 16;
            if (r2 < N_NODES) {
                const unsigned short* ap = Ab + (size_t)(r2 + n15) * 128 + koff;
                #pragma unroll
                for (int ks = 0; ks < 4; ++ks)
                    Afr[slot][ks] = *(const int4*)(ap + ks * 32);
            }
        }
        if (valid) {
            unsigned short* st = stage[w];
            #pragma unroll
            for (int c = 0; c < 8; ++c) {
                float bias = b1[c * 16 + n15];
                #pragma unroll
                for (int r = 0; r < 4; ++r) {
                    float v = acc[c][r] + bias;
                    s[c] += v; q[c] += v * v;
                    st[(quad * 4 + r) * 128 + c * 16 + n15] = f2b(v);
                }
            }
            const size_t gb = (size_t)row0 * 128;
            #pragma unroll
            for (int p = 0; p < 4; ++p)
                *(int4*)(Ab + gb + p * 512 + lane * 8) = *(const int4*)(st + p * 512 + lane * 8);
        }
    }

    #pragma unroll
    for (int c = 0; c < 8; ++c) {
        s[c] += __shfl_down(s[c], 32); q[c] += __shfl_down(q[c], 32);
        s[c] += __shfl_down(s[c], 16); q[c] += __shfl_down(q[c], 16);
    }
    if (quad == 0) {
        #pragma unroll
        for (int c = 0; c < 8; ++c) {
            atomicAdd(&sl[c * 16 + n15], s[c]);
            atomicAdd(&sl[128 + c * 16 + n15], q[c]);
        }
    }
    __syncthreads();
    atomicAdd(&buckets[(blockIdx.x & (NBUCKET - 1)) * 256 + t], sl[t]);
}

// ---------------------------------------------------------------------------
// Fold 64 stat buckets -> BN affine: aff[c]=a, aff[128+c]=beta-mu*a
__global__ void k_finalize(const float* __restrict__ gamma,
                           const float* __restrict__ beta,
                           const float* __restrict__ buckets,
                           float* __restrict__ aff) {
    int c = threadIdx.x;
    if (c < DIM) {
        float s = 0.f, q = 0.f;
        #pragma unroll 8
        for (int b = 0; b < NBUCKET; ++b) {
            s += buckets[b * 256 + c];
            q += buckets[b * 256 + 128 + c];
        }
        float mu  = s * (1.0f / N_NODES);
        float var = q * (1.0f / N_NODES) - mu * mu;
        float a = gamma[c] * rsqrtf(var + BN_EPS);
        aff[c] = a;
        aff[DIM + c] = beta[c] - mu * a;
    }
}

// ===========================================================================
// GEMM2 (MFMA bf16): out = relu(h*a + b) @ W2 + b2, fp32 out. No barriers.
// ===========================================================================
__global__ __launch_bounds__(256) void k_gemm2(const unsigned short* __restrict__ hb,
                                               const unsigned short* __restrict__ Wt2,
                                               const float* __restrict__ aff,
                                               const float* __restrict__ b2,
                                               float* __restrict__ out) {
    __shared__ __align__(16) float stage[4][2048];   // 8 KB per wave
    const int t = threadIdx.x;
    const int w = t >> 6;
    const int lane = t & 63;
    const int n15 = lane & 15;
    const int quad = lane >> 4;
    const int koff = quad * 8;

    const int base_row = blockIdx.x * 256 + w * 64;
    const unsigned short* bp0 = Wt2 + n15 * 128 + koff;

    int4 Afr[2][4];
    #pragma unroll
    for (int sl0 = 0; sl0 < 2; ++sl0) {
        int r0 = base_row + sl0 * 16;
        if (r0 < N_NODES) {
            const unsigned short* ap = hb + (size_t)(r0 + n15) * 128 + koff;
            #pragma unroll
            for (int ks = 0; ks < 4; ++ks)
                Afr[sl0][ks] = *(const int4*)(ap + ks * 32);
        }
    }

    #pragma unroll
    for (int ti = 0; ti < 4; ++ti) {
        const int row0 = base_row + ti * 16;
        const bool valid = row0 < N_NODES;
        const int slot = ti & 1;
        f32x4 acc[8] = {};
        if (valid) {
            #pragma unroll
            for (int ks = 0; ks < 4; ++ks) {
                const int kb = ks * 32 + koff;
                u16x8 ar = __builtin_bit_cast(u16x8, Afr[slot][ks]);
                float ak[8], bk[8];
                *(float4*)(ak)     = *(const float4*)(aff + kb);
                *(float4*)(ak + 4) = *(const float4*)(aff + kb + 4);
                *(float4*)(bk)     = *(const float4*)(aff + 128 + kb);
                *(float4*)(bk + 4) = *(const float4*)(aff + 128 + kb + 4);
                u16x8 pr;
                #pragma unroll
                for (int j = 0; j < 8; ++j) {
                    float f = b2f(ar[j]);
                    f = fmaxf(fmaf(f, ak[j], bk[j]), 0.f);
                    pr[j] = f2b(f);
                }
                bf16x8 af = __builtin_bit_cast(bf16x8, pr);
                const unsigned short* bp = bp0 + ks * 32;
                #pragma unroll
                for (int c = 0; c < 8; ++c) {
                    int4 braw = *(const int4*)(bp + c * 2048);
                    acc[c] = __builtin_amdgcn_mfma_f32_16x16x32_bf16(
                        af, __builtin_bit_cast(bf16x8, braw), acc[c], 0, 0, 0);
                }
            }
        }
        if (ti < 2) {
            int r2 = base_row + (ti + 2) * 16;
            if (r2 < N_NODES) {
                const unsigned short* ap = hb + (size_t)(r2 + n15) * 128 + koff;
                #pragma unroll
                for (int ks = 0; ks < 4; ++ks)
                    Afr[slot][ks] = *(const int4*)(ap + ks * 32);
            }
        }
        if (valid) {
            float* st = stage[w];
            #pragma unroll
            for (int c = 0; c < 8; ++c) {
                float bias = b2[c * 16 + n15];
                #pragma unroll
                for (int r = 0; r < 4; ++r)
                    st[(quad * 4 + r) * 128 + c * 16 + n15] = acc[c][r] + bias;
            }
            const size_t gb = (size_t)row0 * 128;
            #pragma unroll
            for (int p = 0; p < 8; ++p)
                *(float4*)(out + gb + p * 256 + lane * 4) = *(const float4*)(st + p * 256 + lane * 4);
        }
    }
}

// ---------------------------------------------------------------------------
extern "C" void kernel_launch(void* const* d_in, const int* in_sizes, int n_in,
                              void* d_out, int out_size, void* d_ws, size_t ws_size,
                              hipStream_t stream) {
    const float* x     = (const float*)d_in[0];
    const int*   ei    = (const int*)d_in[1];
    const float* W1    = (const float*)d_in[2];
    const float* b1    = (const float*)d_in[3];
    const float* gamma = (const float*)d_in[4];
    const float* beta  = (const float*)d_in[5];
    const float* W2    = (const float*)d_in[6];
    const float* b2    = (const float*)d_in[7];
    const float* eps   = (const float*)d_in[8];
    float* out = (float*)d_out;

    // Workspace: buckets+rowptr adjacent -> single memset.
    float* buckets      = (float*)d_ws;                     // 64*256 floats (64 KB)
    int* rowptr         = (int*)(buckets + NBUCKET * 256);  // N+4 ints
    float* aff          = (float*)(rowptr + N_NODES + 4);   // 256 floats
    unsigned short* Ab  = (unsigned short*)(aff + 256);     // N*128 bf16
    unsigned short* xb  = Ab + (size_t)N_NODES * DIM;       // N*128 bf16
    unsigned short* Wt1 = xb + (size_t)N_NODES * DIM;       // 16384 bf16
    unsigned short* Wt2 = Wt1 + 16384;                      // 16384 bf16
    int* cursor         = (int*)(Wt2 + 16384);              // N
    int* srcidx         = cursor + N_NODES;                 // E
    int* bsum           = srcidx + NEDGE;                   // 128

    hipMemsetAsync(buckets, 0,
                   NBUCKET * 256 * sizeof(float) + (N_NODES + 4) * sizeof(int), stream);

    k_prep<<<PB_X + 2 * PB_W + PB_CNT, 256, 0, stream>>>(x, W1, W2, ei, xb, Wt1, Wt2, rowptr);
    k_scan1<<<NB_SCAN, 256, 0, stream>>>(rowptr, bsum);
    k_scan_mid<<<1, 128, 0, stream>>>(bsum);
    k_scan_add<<<NB_SCAN, 256, 0, stream>>>(rowptr, bsum, cursor);
    k_fill<<<(NEDGE + 255) / 256, 256, 0, stream>>>(ei, cursor, srcidx);
    k_aggregate<<<(N_NODES * 64) / 256, 256, 0, stream>>>(xb, rowptr, srcidx, eps, Ab);
    k_gemm1<<<GBLK, 256, 0, stream>>>(Ab, Wt1, b1, buckets);
    k_finalize<<<1, 128, 0, stream>>>(gamma, beta, buckets, aff);
    k_gemm2<<<GBLK, 256, 0, stream>>>(Ab, Wt2, aff, b2, out);
}

// Round 7
// 270.571 us; speedup vs baseline: 1.1304x; 1.1304x over previous
//
#include <hip/hip_runtime.h>

#define N_NODES 100000
#define DIM     128
#define NEDGE   640000
#define BN_EPS  1e-5f
#define NB_SCAN 98      // ceil(100000/1024)

// k_prep block ranges
#define PB_X    6250    // 12.8M elems / (256 thr * 8)
#define PB_W    64      // 16384 / 256
#define PB_CNT  2500    // 640000 / 256

#define NBUCKET 64
#define GGRID   782     // ceil(6250 tiles / 8 tiles-per-block)

typedef __bf16 bf16x8 __attribute__((ext_vector_type(8)));
typedef float  f32x4  __attribute__((ext_vector_type(4)));
typedef unsigned short u16x8 __attribute__((ext_vector_type(8)));

__device__ __forceinline__ unsigned short f2b(float f) {
    unsigned u = __builtin_bit_cast(unsigned, f);
    u += 0x7fffu + ((u >> 16) & 1u);            // RNE
    return (unsigned short)(u >> 16);
}
__device__ __forceinline__ float b2f(unsigned short b) {
    return __builtin_bit_cast(float, ((unsigned)b) << 16);
}

// ===========================================================================
// Fused prep: x->bf16, W1/W2 transpose->bf16, degree count.
// ===========================================================================
__global__ __launch_bounds__(256) void k_prep(const float* __restrict__ x,
                                              const float* __restrict__ W1,
                                              const float* __restrict__ W2,
                                              const int* __restrict__ ei,
                                              unsigned short* __restrict__ xb,
                                              unsigned short* __restrict__ Wt1,
                                              unsigned short* __restrict__ Wt2,
                                              int* __restrict__ rowptr) {
    const int b = blockIdx.x;
    const int t = threadIdx.x;
    if (b < PB_X) {
        size_t base = ((size_t)b * 256 + t) * 8;
        float4 v0 = *(const float4*)(x + base);
        float4 v1 = *(const float4*)(x + base + 4);
        u16x8 o;
        o[0] = f2b(v0.x); o[1] = f2b(v0.y); o[2] = f2b(v0.z); o[3] = f2b(v0.w);
        o[4] = f2b(v1.x); o[5] = f2b(v1.y); o[6] = f2b(v1.z); o[7] = f2b(v1.w);
        *(u16x8*)(xb + base) = o;
    } else if (b < PB_X + PB_W) {
        int idx = (b - PB_X) * 256 + t;
        int k = idx >> 7, n = idx & 127;
        Wt1[n * 128 + k] = f2b(W1[idx]);
    } else if (b < PB_X + 2 * PB_W) {
        int idx = (b - PB_X - PB_W) * 256 + t;
        int k = idx >> 7, n = idx & 127;
        Wt2[n * 128 + k] = f2b(W2[idx]);
    } else {
        int e = (b - PB_X - 2 * PB_W) * 256 + t;
        if (e < NEDGE) atomicAdd(&rowptr[ei[NEDGE + e]], 1);
    }
}

// ===========================================================================
// CSR scan + fill
// ===========================================================================
__global__ __launch_bounds__(256) void k_scan1(int* __restrict__ rowptr,
                                               int* __restrict__ bsum) {
    __shared__ int tsum[256];
    const int t = threadIdx.x;
    const int base = blockIdx.x * 1024 + t * 4;
    int v[4];
    #pragma unroll
    for (int j = 0; j < 4; ++j)
        v[j] = (base + j < N_NODES) ? rowptr[base + j] : 0;
    int s = v[0] + v[1] + v[2] + v[3];
    tsum[t] = s;
    __syncthreads();
    #pragma unroll
    for (int off = 1; off < 256; off <<= 1) {
        int a = tsum[t];
        int b = (t >= off) ? tsum[t - off] : 0;
        __syncthreads();
        tsum[t] = a + b;
        __syncthreads();
    }
    int run = tsum[t] - s;
    #pragma unroll
    for (int j = 0; j < 4; ++j) {
        int nv = run;
        run += v[j];
        if (base + j < N_NODES) rowptr[base + j] = nv;
    }
    if (t == 255) bsum[blockIdx.x] = tsum[255];
}

__global__ __launch_bounds__(128) void k_scan_mid(int* __restrict__ bsum) {
    __shared__ int sh[128];
    const int t = threadIdx.x;
    int orig = (t < NB_SCAN) ? bsum[t] : 0;
    sh[t] = orig;
    __syncthreads();
    #pragma unroll
    for (int off = 1; off < 128; off <<= 1) {
        int a = sh[t];
        int b = (t >= off) ? sh[t - off] : 0;
        __syncthreads();
        sh[t] = a + b;
        __syncthreads();
    }
    if (t < NB_SCAN) bsum[t] = sh[t] - orig;
}

__global__ __launch_bounds__(256) void k_scan_add(int* __restrict__ rowptr,
                                                  const int* __restrict__ bsum,
                                                  int* __restrict__ cursor) {
    const int t = threadIdx.x;
    const int base = blockIdx.x * 1024 + t * 4;
    const int add = bsum[blockIdx.x];
    #pragma unroll
    for (int j = 0; j < 4; ++j) {
        if (base + j < N_NODES) {
            int r = rowptr[base + j] + add;
            rowptr[base + j] = r;
            cursor[base + j] = r;
        }
    }
    if (blockIdx.x == 0 && t == 0) rowptr[N_NODES] = NEDGE;
}

__global__ __launch_bounds__(256) void k_fill(const int* __restrict__ ei,
                                              int* __restrict__ cursor,
                                              int* __restrict__ srcidx) {
    int e = blockIdx.x * 256 + threadIdx.x;
    if (e < NEDGE) {
        int dst = ei[NEDGE + e];
        int pos = atomicAdd(&cursor[dst], 1);
        srcidx[pos] = ei[e];
    }
}

// ===========================================================================
// Pull aggregation (bf16 gather, 4 edges per load instruction).
// ===========================================================================
__global__ __launch_bounds__(256) void k_aggregate(const unsigned short* __restrict__ xb,
                                                   const int* __restrict__ rowptr,
                                                   const int* __restrict__ srcidx,
                                                   const float* __restrict__ epsp,
                                                   unsigned short* __restrict__ Ab) {
    const int wid  = (blockIdx.x * 256 + threadIdx.x) >> 6;
    const int lane = threadIdx.x & 63;
    if (wid >= N_NODES) return;
    const int g = lane >> 4;        // edge group 0..3
    const int c = (lane & 15) * 8;  // col offset
    const float scale = 1.0f + epsp[0];
    const int beg = rowptr[wid];
    const int end = rowptr[wid + 1];

    float acc[8] = {0.f, 0.f, 0.f, 0.f, 0.f, 0.f, 0.f, 0.f};
    for (int p = beg; p < end; p += 4) {
        int e = p + g;
        if (e < end) {
            int s = srcidx[e];
            u16x8 v = *(const u16x8*)(xb + (size_t)s * 128 + c);
            #pragma unroll
            for (int j = 0; j < 8; ++j) acc[j] += b2f(v[j]);
        }
    }
    if (g == 0) {
        u16x8 v = *(const u16x8*)(xb + (size_t)wid * 128 + c);
        #pragma unroll
        for (int j = 0; j < 8; ++j) acc[j] = fmaf(scale, b2f(v[j]), acc[j]);
    }
    #pragma unroll
    for (int j = 0; j < 8; ++j) acc[j] += __shfl_down(acc[j], 32);
    #pragma unroll
    for (int j = 0; j < 8; ++j) acc[j] += __shfl_down(acc[j], 16);
    if (lane < 16) {
        u16x8 o;
        #pragma unroll
        for (int j = 0; j < 8; ++j) o[j] = f2b(acc[j]);
        *(u16x8*)(Ab + (size_t)wid * 128 + c) = o;
    }
}

// ===========================================================================
// GEMM1 (MFMA bf16): h = A @ W1 + b1 -> hB (NOT in-place: col-split waves
// share rows, so in-place write races with the other wave's A prefetch).
// B in registers; wave owns a 64-col half, streams 4 M-tiles, depth-1 A prefetch.
// ===========================================================================
__global__ __launch_bounds__(256) void k_gemm1(const unsigned short* __restrict__ Ab,
                                               unsigned short* __restrict__ hB,
                                               const unsigned short* __restrict__ Wt,
                                               const float* __restrict__ b1,
                                               float* __restrict__ buckets) {
    __shared__ __align__(16) unsigned short stage[4][1024];  // 2 KB/wave: 16r x 64c bf16
    __shared__ float sl[256];
    const int t = threadIdx.x;
    const int w = t >> 6;
    const int lane = t & 63;
    const int n15 = lane & 15;
    const int quad = lane >> 4;
    const int half = w & 1;          // column half (0: cols 0-63, 1: 64-127)
    sl[t] = 0.f;
    __syncthreads();

    // B fragments in registers: 4 col-tiles x 4 k-steps
    int4 Bfr[4][4];
    const unsigned short* wp = Wt + (half * 64 + n15) * 128 + quad * 8;
    #pragma unroll
    for (int c = 0; c < 4; ++c)
        #pragma unroll
        for (int ks = 0; ks < 4; ++ks)
            Bfr[c][ks] = *(const int4*)(wp + c * 16 * 128 + ks * 32);

    float bias[4];
    #pragma unroll
    for (int c = 0; c < 4; ++c) bias[c] = b1[half * 64 + c * 16 + n15];

    const int tile0 = blockIdx.x * 8 + (w >> 1) * 4;
    int4 Acur[4], Anxt[4];
    {
        int r0 = tile0 * 16;
        if (r0 < N_NODES) {
            const unsigned short* ap = Ab + (size_t)(r0 + n15) * 128 + quad * 8;
            #pragma unroll
            for (int ks = 0; ks < 4; ++ks) Acur[ks] = *(const int4*)(ap + ks * 32);
        }
    }

    float s[4] = {0.f, 0.f, 0.f, 0.f};
    float q[4] = {0.f, 0.f, 0.f, 0.f};
    unsigned short* st = stage[w];

    #pragma unroll
    for (int i = 0; i < 4; ++i) {
        const int row0 = (tile0 + i) * 16;
        const bool valid = row0 < N_NODES;
        if (i < 3) {
            int rn = (tile0 + i + 1) * 16;
            if (rn < N_NODES) {
                const unsigned short* ap = Ab + (size_t)(rn + n15) * 128 + quad * 8;
                #pragma unroll
                for (int ks = 0; ks < 4; ++ks) Anxt[ks] = *(const int4*)(ap + ks * 32);
            }
        }
        if (valid) {
            f32x4 acc[4] = {};
            #pragma unroll
            for (int ks = 0; ks < 4; ++ks) {
                bf16x8 af = __builtin_bit_cast(bf16x8, Acur[ks]);
                #pragma unroll
                for (int c = 0; c < 4; ++c)
                    acc[c] = __builtin_amdgcn_mfma_f32_16x16x32_bf16(
                        af, __builtin_bit_cast(bf16x8, Bfr[c][ks]), acc[c], 0, 0, 0);
            }
            #pragma unroll
            for (int c = 0; c < 4; ++c)
                #pragma unroll
                for (int r = 0; r < 4; ++r) {
                    float v = acc[c][r] + bias[c];
                    s[c] += v; q[c] += v * v;
                    st[(quad * 4 + r) * 64 + c * 16 + n15] = f2b(v);
                }
            // store 16 rows x 64 cols bf16: 2 passes, 8 lanes cover one row (128 B)
            #pragma unroll
            for (int p = 0; p < 2; ++p) {
                int soff = p * 512 + lane * 8;
                int r = soff >> 6, cc = soff & 63;
                *(int4*)(hB + (size_t)(row0 + r) * 128 + half * 64 + cc) =
                    *(const int4*)(st + soff);
            }
        }
        #pragma unroll
        for (int ks = 0; ks < 4; ++ks) Acur[ks] = Anxt[ks];
    }

    #pragma unroll
    for (int c = 0; c < 4; ++c) {
        s[c] += __shfl_down(s[c], 32); q[c] += __shfl_down(q[c], 32);
        s[c] += __shfl_down(s[c], 16); q[c] += __shfl_down(q[c], 16);
    }
    if (quad == 0) {
        #pragma unroll
        for (int c = 0; c < 4; ++c) {
            atomicAdd(&sl[half * 64 + c * 16 + n15], s[c]);
            atomicAdd(&sl[128 + half * 64 + c * 16 + n15], q[c]);
        }
    }
    __syncthreads();
    atomicAdd(&buckets[(blockIdx.x & (NBUCKET - 1)) * 256 + t], sl[t]);
}

// ---------------------------------------------------------------------------
// Fold 64 stat buckets -> BN affine: aff[c]=a, aff[128+c]=beta-mu*a
__global__ void k_finalize(const float* __restrict__ gamma,
                           const float* __restrict__ beta,
                           const float* __restrict__ buckets,
                           float* __restrict__ aff) {
    int c = threadIdx.x;
    if (c < DIM) {
        float s = 0.f, q = 0.f;
        #pragma unroll 8
        for (int b = 0; b < NBUCKET; ++b) {
            s += buckets[b * 256 + c];
            q += buckets[b * 256 + 128 + c];
        }
        float mu  = s * (1.0f / N_NODES);
        float var = q * (1.0f / N_NODES) - mu * mu;
        float a = gamma[c] * rsqrtf(var + BN_EPS);
        aff[c] = a;
        aff[DIM + c] = beta[c] - mu * a;
    }
}

// ===========================================================================
// GEMM2 (MFMA bf16): out = relu(h*a + b) @ W2 + b2, fp32 out.
// Same register-B structure; BN affine hoisted to registers per wave.
// ===========================================================================
__global__ __launch_bounds__(256) void k_gemm2(const unsigned short* __restrict__ hb,
                                               const unsigned short* __restrict__ Wt2,
                                               const float* __restrict__ aff,
                                               const float* __restrict__ b2,
                                               float* __restrict__ out) {
    __shared__ __align__(16) float stage[4][1024];   // 4 KB/wave: 16r x 64c fp32
    const int t = threadIdx.x;
    const int w = t >> 6;
    const int lane = t & 63;
    const int n15 = lane & 15;
    const int quad = lane >> 4;
    const int half = w & 1;

    int4 Bfr[4][4];
    const unsigned short* wp = Wt2 + (half * 64 + n15) * 128 + quad * 8;
    #pragma unroll
    for (int c = 0; c < 4; ++c)
        #pragma unroll
        for (int ks = 0; ks < 4; ++ks)
            Bfr[c][ks] = *(const int4*)(wp + c * 16 * 128 + ks * 32);

    // BN affine for this lane's k-positions (k = ks*32 + quad*8 + j)
    float ak[4][8], bk[4][8];
    #pragma unroll
    for (int ks = 0; ks < 4; ++ks) {
        const int kb = ks * 32 + quad * 8;
        *(float4*)(&ak[ks][0]) = *(const float4*)(aff + kb);
        *(float4*)(&ak[ks][4]) = *(const float4*)(aff + kb + 4);
        *(float4*)(&bk[ks][0]) = *(const float4*)(aff + 128 + kb);
        *(float4*)(&bk[ks][4]) = *(const float4*)(aff + 128 + kb + 4);
    }
    float bias[4];
    #pragma unroll
    for (int c = 0; c < 4; ++c) bias[c] = b2[half * 64 + c * 16 + n15];

    const int tile0 = blockIdx.x * 8 + (w >> 1) * 4;
    int4 Acur[4], Anxt[4];
    {
        int r0 = tile0 * 16;
        if (r0 < N_NODES) {
            const unsigned short* ap = hb + (size_t)(r0 + n15) * 128 + quad * 8;
            #pragma unroll
            for (int ks = 0; ks < 4; ++ks) Acur[ks] = *(const int4*)(ap + ks * 32);
        }
    }
    float* st = stage[w];

    #pragma unroll
    for (int i = 0; i < 4; ++i) {
        const int row0 = (tile0 + i) * 16;
        const bool valid = row0 < N_NODES;
        if (i < 3) {
            int rn = (tile0 + i + 1) * 16;
            if (rn < N_NODES) {
                const unsigned short* ap = hb + (size_t)(rn + n15) * 128 + quad * 8;
                #pragma unroll
                for (int ks = 0; ks < 4; ++ks) Anxt[ks] = *(const int4*)(ap + ks * 32);
            }
        }
        if (valid) {
            f32x4 acc[4] = {};
            #pragma unroll
            for (int ks = 0; ks < 4; ++ks) {
                u16x8 ar = __builtin_bit_cast(u16x8, Acur[ks]);
                u16x8 pr;
                #pragma unroll
                for (int j = 0; j < 8; ++j) {
                    float f = b2f(ar[j]);
                    f = fmaxf(fmaf(f, ak[ks][j], bk[ks][j]), 0.f);
                    pr[j] = f2b(f);
                }
                bf16x8 af = __builtin_bit_cast(bf16x8, pr);
                #pragma unroll
                for (int c = 0; c < 4; ++c)
                    acc[c] = __builtin_amdgcn_mfma_f32_16x16x32_bf16(
                        af, __builtin_bit_cast(bf16x8, Bfr[c][ks]), acc[c], 0, 0, 0);
            }
            #pragma unroll
            for (int c = 0; c < 4; ++c)
                #pragma unroll
                for (int r = 0; r < 4; ++r)
                    st[(quad * 4 + r) * 64 + c * 16 + n15] = acc[c][r] + bias[c];
            // store 16 rows x 64 cols fp32: 4 passes, 16 lanes cover one row (256 B)
            #pragma unroll
            for (int p = 0; p < 4; ++p) {
                int foff = p * 256 + lane * 4;
                int r = foff >> 6, cc = foff & 63;
                *(float4*)(out + (size_t)(row0 + r) * 128 + half * 64 + cc) =
                    *(const float4*)(st + foff);
            }
        }
        #pragma unroll
        for (int ks = 0; ks < 4; ++ks) Acur[ks] = Anxt[ks];
    }
}

// ---------------------------------------------------------------------------
extern "C" void kernel_launch(void* const* d_in, const int* in_sizes, int n_in,
                              void* d_out, int out_size, void* d_ws, size_t ws_size,
                              hipStream_t stream) {
    const float* x     = (const float*)d_in[0];
    const int*   ei    = (const int*)d_in[1];
    const float* W1    = (const float*)d_in[2];
    const float* b1    = (const float*)d_in[3];
    const float* gamma = (const float*)d_in[4];
    const float* beta  = (const float*)d_in[5];
    const float* W2    = (const float*)d_in[6];
    const float* b2    = (const float*)d_in[7];
    const float* eps   = (const float*)d_in[8];
    float* out = (float*)d_out;

    // Workspace: buckets+rowptr adjacent -> single memset.
    // xb doubles as the h buffer for GEMM1 output (dead after k_aggregate).
    float* buckets      = (float*)d_ws;                     // 64*256 floats (64 KB)
    int* rowptr         = (int*)(buckets + NBUCKET * 256);  // N+4 ints
    float* aff          = (float*)(rowptr + N_NODES + 4);   // 256 floats
    unsigned short* Ab  = (unsigned short*)(aff + 256);     // N*128 bf16
    unsigned short* xb  = Ab + (size_t)N_NODES * DIM;       // N*128 bf16 (x, then h)
    unsigned short* Wt1 = xb + (size_t)N_NODES * DIM;       // 16384 bf16
    unsigned short* Wt2 = Wt1 + 16384;                      // 16384 bf16
    int* cursor         = (int*)(Wt2 + 16384);              // N
    int* srcidx         = cursor + N_NODES;                 // E
    int* bsum           = srcidx + NEDGE;                   // 128

    hipMemsetAsync(buckets, 0,
                   NBUCKET * 256 * sizeof(float) + (N_NODES + 4) * sizeof(int), stream);

    k_prep<<<PB_X + 2 * PB_W + PB_CNT, 256, 0, stream>>>(x, W1, W2, ei, xb, Wt1, Wt2, rowptr);
    k_scan1<<<NB_SCAN, 256, 0, stream>>>(rowptr, bsum);
    k_scan_mid<<<1, 128, 0, stream>>>(bsum);
    k_scan_add<<<NB_SCAN, 256, 0, stream>>>(rowptr, bsum, cursor);
    k_fill<<<(NEDGE + 255) / 256, 256, 0, stream>>>(ei, cursor, srcidx);
    k_aggregate<<<(N_NODES * 64) / 256, 256, 0, stream>>>(xb, rowptr, srcidx, eps, Ab);
    k_gemm1<<<GGRID, 256, 0, stream>>>(Ab, xb, Wt1, b1, buckets);   // h -> xb
    k_finalize<<<1, 128, 0, stream>>>(gamma, beta, buckets, aff);
    k_gemm2<<<GGRID, 256, 0, stream>>>(xb, Wt2, aff, b2, out);
}

// Round 8
// 260.942 us; speedup vs baseline: 1.1722x; 1.0369x over previous
//
#include <hip/hip_runtime.h>

#define N_NODES 100000
#define DIM     128
#define NEDGE   640000
#define BN_EPS  1e-5f
#define NB_SCAN 98      // ceil(100000/1024)

// k_prep block ranges
#define PB_X    6250    // 12.8M elems / (256 thr * 8)
#define PB_W    64      // 16384 / 256
#define PB_CNT  2500    // 640000 / 256

#define NBUCKET 64
#define T_TILES 4
#define GGRID   1563    // ceil(6250 tiles / 4 tiles-per-block)

typedef __bf16 bf16x8 __attribute__((ext_vector_type(8)));
typedef float  f32x4  __attribute__((ext_vector_type(4)));
typedef unsigned short u16x8 __attribute__((ext_vector_type(8)));

__device__ __forceinline__ unsigned short f2b(float f) {
    unsigned u = __builtin_bit_cast(unsigned, f);
    u += 0x7fffu + ((u >> 16) & 1u);            // RNE
    return (unsigned short)(u >> 16);
}
__device__ __forceinline__ float b2f(unsigned short b) {
    return __builtin_bit_cast(float, ((unsigned)b) << 16);
}

// ===========================================================================
// Fused prep: x->bf16, W1/W2 transpose->bf16, degree count.
// ===========================================================================
__global__ __launch_bounds__(256) void k_prep(const float* __restrict__ x,
                                              const float* __restrict__ W1,
                                              const float* __restrict__ W2,
                                              const int* __restrict__ ei,
                                              unsigned short* __restrict__ xb,
                                              unsigned short* __restrict__ Wt1,
                                              unsigned short* __restrict__ Wt2,
                                              int* __restrict__ rowptr) {
    const int b = blockIdx.x;
    const int t = threadIdx.x;
    if (b < PB_X) {
        size_t base = ((size_t)b * 256 + t) * 8;
        float4 v0 = *(const float4*)(x + base);
        float4 v1 = *(const float4*)(x + base + 4);
        u16x8 o;
        o[0] = f2b(v0.x); o[1] = f2b(v0.y); o[2] = f2b(v0.z); o[3] = f2b(v0.w);
        o[4] = f2b(v1.x); o[5] = f2b(v1.y); o[6] = f2b(v1.z); o[7] = f2b(v1.w);
        *(u16x8*)(xb + base) = o;
    } else if (b < PB_X + PB_W) {
        int idx = (b - PB_X) * 256 + t;
        int k = idx >> 7, n = idx & 127;
        Wt1[n * 128 + k] = f2b(W1[idx]);
    } else if (b < PB_X + 2 * PB_W) {
        int idx = (b - PB_X - PB_W) * 256 + t;
        int k = idx >> 7, n = idx & 127;
        Wt2[n * 128 + k] = f2b(W2[idx]);
    } else {
        int e = (b - PB_X - 2 * PB_W) * 256 + t;
        if (e < NEDGE) atomicAdd(&rowptr[ei[NEDGE + e]], 1);
    }
}

// ===========================================================================
// CSR scan + fill
// ===========================================================================
__global__ __launch_bounds__(256) void k_scan1(int* __restrict__ rowptr,
                                               int* __restrict__ bsum) {
    __shared__ int tsum[256];
    const int t = threadIdx.x;
    const int base = blockIdx.x * 1024 + t * 4;
    int v[4];
    #pragma unroll
    for (int j = 0; j < 4; ++j)
        v[j] = (base + j < N_NODES) ? rowptr[base + j] : 0;
    int s = v[0] + v[1] + v[2] + v[3];
    tsum[t] = s;
    __syncthreads();
    #pragma unroll
    for (int off = 1; off < 256; off <<= 1) {
        int a = tsum[t];
        int b = (t >= off) ? tsum[t - off] : 0;
        __syncthreads();
        tsum[t] = a + b;
        __syncthreads();
    }
    int run = tsum[t] - s;
    #pragma unroll
    for (int j = 0; j < 4; ++j) {
        int nv = run;
        run += v[j];
        if (base + j < N_NODES) rowptr[base + j] = nv;
    }
    if (t == 255) bsum[blockIdx.x] = tsum[255];
}

// scan_add with the 98-entry mid-scan folded in (drops one kernel launch).
__global__ __launch_bounds__(256) void k_scan_add(int* __restrict__ rowptr,
                                                  const int* __restrict__ bsum,
                                                  int* __restrict__ cursor) {
    __shared__ int sh[128];
    const int t = threadIdx.x;
    if (t < 128) sh[t] = (t < NB_SCAN) ? bsum[t] : 0;
    __syncthreads();
    #pragma unroll
    for (int off = 1; off < 128; off <<= 1) {
        int a = 0, b = 0;
        if (t < 128) { a = sh[t]; b = (t >= off) ? sh[t - off] : 0; }
        __syncthreads();
        if (t < 128) sh[t] = a + b;
        __syncthreads();
    }
    const int add = (blockIdx.x > 0) ? sh[blockIdx.x - 1] : 0;  // exclusive prefix
    const int base = blockIdx.x * 1024 + t * 4;
    #pragma unroll
    for (int j = 0; j < 4; ++j) {
        if (base + j < N_NODES) {
            int r = rowptr[base + j] + add;
            rowptr[base + j] = r;
            cursor[base + j] = r;
        }
    }
    if (blockIdx.x == 0 && t == 0) rowptr[N_NODES] = NEDGE;
}

__global__ __launch_bounds__(256) void k_fill(const int* __restrict__ ei,
                                              int* __restrict__ cursor,
                                              int* __restrict__ srcidx) {
    int e = blockIdx.x * 256 + threadIdx.x;
    if (e < NEDGE) {
        int dst = ei[NEDGE + e];
        int pos = atomicAdd(&cursor[dst], 1);
        srcidx[pos] = ei[e];
    }
}

// ===========================================================================
// Pull aggregation (bf16 gather): one wave per node, 4 edge-groups of 16
// lanes, unrolled x2 so two gather chains are in flight per iteration.
// ===========================================================================
__global__ __launch_bounds__(256) void k_aggregate(const unsigned short* __restrict__ xb,
                                                   const int* __restrict__ rowptr,
                                                   const int* __restrict__ srcidx,
                                                   const float* __restrict__ epsp,
                                                   unsigned short* __restrict__ Ab) {
    const int wid  = (blockIdx.x * 256 + threadIdx.x) >> 6;
    const int lane = threadIdx.x & 63;
    if (wid >= N_NODES) return;
    const int g = lane >> 4;        // edge group 0..3
    const int c = (lane & 15) * 8;  // col offset
    const float scale = 1.0f + epsp[0];
    const int beg = rowptr[wid];
    const int end = rowptr[wid + 1];

    float acc[8] = {0.f, 0.f, 0.f, 0.f, 0.f, 0.f, 0.f, 0.f};
    if (g == 0) {   // self term first; overlaps with loop's first gathers
        u16x8 v = *(const u16x8*)(xb + (size_t)wid * 128 + c);
        #pragma unroll
        for (int j = 0; j < 8; ++j) acc[j] = scale * b2f(v[j]);
    }
    for (int p = beg; p < end; p += 8) {
        const int e0 = p + g;
        const int e1 = p + g + 4;
        const bool h0 = e0 < end;
        const bool h1 = e1 < end;
        u16x8 v0, v1;
        if (h0) {
            int s0 = srcidx[e0];
            v0 = *(const u16x8*)(xb + (size_t)s0 * 128 + c);
        }
        if (h1) {
            int s1 = srcidx[e1];
            v1 = *(const u16x8*)(xb + (size_t)s1 * 128 + c);
        }
        if (h0) {
            #pragma unroll
            for (int j = 0; j < 8; ++j) acc[j] += b2f(v0[j]);
        }
        if (h1) {
            #pragma unroll
            for (int j = 0; j < 8; ++j) acc[j] += b2f(v1[j]);
        }
    }
    #pragma unroll
    for (int j = 0; j < 8; ++j) acc[j] += __shfl_down(acc[j], 32);
    #pragma unroll
    for (int j = 0; j < 8; ++j) acc[j] += __shfl_down(acc[j], 16);
    if (lane < 16) {
        u16x8 o;
        #pragma unroll
        for (int j = 0; j < 8; ++j) o[j] = f2b(acc[j]);
        *(u16x8*)(Ab + (size_t)wid * 128 + c) = o;
    }
}

// ===========================================================================
// GEMM1 (MFMA bf16): h = A @ W1 + b1 -> hB (bf16) + bucketed stats.
// 4-way column split (wave w owns cols w*32..w*32+31; Bfr = 32 VGPR),
// T_TILES tiles per block with depth-1 A prefetch, direct global A loads.
// ===========================================================================
__global__ __launch_bounds__(256) void k_gemm1(const unsigned short* __restrict__ Ab,
                                               unsigned short* __restrict__ hB,
                                               const unsigned short* __restrict__ Wt,
                                               const float* __restrict__ b1,
                                               float* __restrict__ buckets) {
    __shared__ float sl[256];
    __shared__ __align__(16) unsigned short stage[4][512];  // 1 KB/wave
    const int t = threadIdx.x;
    const int w = t >> 6;
    const int lane = t & 63;
    const int n15 = lane & 15;
    const int quad = lane >> 4;

    int4 Bfr[2][4];
    const unsigned short* wp = Wt + (w * 32 + n15) * 128 + quad * 8;
    #pragma unroll
    for (int c = 0; c < 2; ++c)
        #pragma unroll
        for (int ks = 0; ks < 4; ++ks)
            Bfr[c][ks] = *(const int4*)(wp + c * 16 * 128 + ks * 32);

    float bias[2] = { b1[w * 32 + n15], b1[w * 32 + 16 + n15] };

    const int tile0 = blockIdx.x * T_TILES;
    int4 Acur[4], Anxt[4];
    {
        int r0 = tile0 * 16;
        if (r0 < N_NODES) {
            const unsigned short* ap = Ab + (size_t)(r0 + n15) * 128 + quad * 8;
            #pragma unroll
            for (int ks = 0; ks < 4; ++ks) Acur[ks] = *(const int4*)(ap + ks * 32);
        }
    }

    float s[2] = {0.f, 0.f}, q[2] = {0.f, 0.f};
    unsigned short* st = stage[w];

    #pragma unroll
    for (int i = 0; i < T_TILES; ++i) {
        const int row0 = (tile0 + i) * 16;
        const bool valid = row0 < N_NODES;
        if (i + 1 < T_TILES) {
            int rn = (tile0 + i + 1) * 16;
            if (rn < N_NODES) {
                const unsigned short* ap = Ab + (size_t)(rn + n15) * 128 + quad * 8;
                #pragma unroll
                for (int ks = 0; ks < 4; ++ks) Anxt[ks] = *(const int4*)(ap + ks * 32);
            }
        }
        if (valid) {
            f32x4 acc[2] = {};
            #pragma unroll
            for (int ks = 0; ks < 4; ++ks) {
                bf16x8 af = __builtin_bit_cast(bf16x8, Acur[ks]);
                #pragma unroll
                for (int c = 0; c < 2; ++c)
                    acc[c] = __builtin_amdgcn_mfma_f32_16x16x32_bf16(
                        af, __builtin_bit_cast(bf16x8, Bfr[c][ks]), acc[c], 0, 0, 0);
            }
            #pragma unroll
            for (int c = 0; c < 2; ++c)
                #pragma unroll
                for (int r = 0; r < 4; ++r) {
                    float v = acc[c][r] + bias[c];
                    s[c] += v; q[c] += v * v;
                    st[(quad * 4 + r) * 32 + c * 16 + n15] = f2b(v);
                }
            // 16 rows x 32 cols bf16 = 1 KB: one pass of 64 lanes x 16 B
            int so = lane * 8;
            int r = so >> 5, cc = so & 31;
            *(int4*)(hB + (size_t)(row0 + r) * 128 + w * 32 + cc) = *(const int4*)(st + so);
        }
        #pragma unroll
        for (int ks = 0; ks < 4; ++ks) Acur[ks] = Anxt[ks];
    }

    #pragma unroll
    for (int c = 0; c < 2; ++c) {
        s[c] += __shfl_down(s[c], 32); q[c] += __shfl_down(q[c], 32);
        s[c] += __shfl_down(s[c], 16); q[c] += __shfl_down(q[c], 16);
    }
    if (quad == 0) {   // unique writer per slot: plain stores, full coverage
        #pragma unroll
        for (int c = 0; c < 2; ++c) {
            sl[w * 32 + c * 16 + n15] = s[c];
            sl[128 + w * 32 + c * 16 + n15] = q[c];
        }
    }
    __syncthreads();
    atomicAdd(&buckets[(blockIdx.x & (NBUCKET - 1)) * 256 + t], sl[t]);
}

// ---------------------------------------------------------------------------
// Fold 64 stat buckets -> BN affine: aff[c]=a, aff[128+c]=beta-mu*a
__global__ void k_finalize(const float* __restrict__ gamma,
                           const float* __restrict__ beta,
                           const float* __restrict__ buckets,
                           float* __restrict__ aff) {
    int c = threadIdx.x;
    if (c < DIM) {
        float s = 0.f, q = 0.f;
        #pragma unroll 8
        for (int b = 0; b < NBUCKET; ++b) {
            s += buckets[b * 256 + c];
            q += buckets[b * 256 + 128 + c];
        }
        float mu  = s * (1.0f / N_NODES);
        float var = q * (1.0f / N_NODES) - mu * mu;
        float a = gamma[c] * rsqrtf(var + BN_EPS);
        aff[c] = a;
        aff[DIM + c] = beta[c] - mu * a;
    }
}

// ===========================================================================
// GEMM2 (MFMA bf16): out = relu(h*a + b) @ W2 + b2, fp32 out.
// 4-way column split. BN+ReLU+bf16 transform applied ONCE per element:
// wave w transforms its own k-quarter (akr/bkr = 16 VGPR) into a
// double-buffered LDS A-tile; one barrier per tile; all waves ds_read frags.
// ===========================================================================
__global__ __launch_bounds__(256) void k_gemm2(const unsigned short* __restrict__ hb,
                                               const unsigned short* __restrict__ Wt2,
                                               const float* __restrict__ aff,
                                               const float* __restrict__ b2,
                                               float* __restrict__ out) {
    __shared__ __align__(16) unsigned short Asb[2][16 * 136];  // 8.5 KB dbuf
    __shared__ __align__(16) float stage[4][512];              // 2 KB/wave
    const int t = threadIdx.x;
    const int w = t >> 6;
    const int lane = t & 63;
    const int n15 = lane & 15;
    const int quad = lane >> 4;
    const int kb = w * 32 + quad * 8;    // this wave's k-quarter slice for lane

    int4 Bfr[2][4];
    const unsigned short* wp = Wt2 + (w * 32 + n15) * 128 + quad * 8;
    #pragma unroll
    for (int c = 0; c < 2; ++c)
        #pragma unroll
        for (int ks = 0; ks < 4; ++ks)
            Bfr[c][ks] = *(const int4*)(wp + c * 16 * 128 + ks * 32);

    float akr[8], bkr[8];
    *(float4*)(akr)     = *(const float4*)(aff + kb);
    *(float4*)(akr + 4) = *(const float4*)(aff + kb + 4);
    *(float4*)(bkr)     = *(const float4*)(aff + 128 + kb);
    *(float4*)(bkr + 4) = *(const float4*)(aff + 128 + kb + 4);
    float bias[2] = { b2[w * 32 + n15], b2[w * 32 + 16 + n15] };

    const int tile0 = blockIdx.x * T_TILES;
    int4 gr;
    {
        int r0 = tile0 * 16;
        if (r0 < N_NODES)
            gr = *(const int4*)(hb + (size_t)(r0 + n15) * 128 + kb);
    }
    float* st = stage[w];

    #pragma unroll
    for (int i = 0; i < T_TILES; ++i) {
        const int row0 = (tile0 + i) * 16;
        const bool valid = row0 < N_NODES;   // block-uniform
        unsigned short* al = Asb[i & 1];
        if (valid) {
            u16x8 ar = __builtin_bit_cast(u16x8, gr);
            u16x8 pr;
            #pragma unroll
            for (int j = 0; j < 8; ++j)
                pr[j] = f2b(fmaxf(fmaf(b2f(ar[j]), akr[j], bkr[j]), 0.f));
            *(int4*)(al + n15 * 136 + kb) = __builtin_bit_cast(int4, pr);
        }
        if (i + 1 < T_TILES) {
            int rn = (tile0 + i + 1) * 16;
            if (rn < N_NODES)
                gr = *(const int4*)(hb + (size_t)(rn + n15) * 128 + kb);
        }
        __syncthreads();
        if (valid) {
            f32x4 acc[2] = {};
            #pragma unroll
            for (int ks = 0; ks < 4; ++ks) {
                int4 araw = *(const int4*)(al + n15 * 136 + ks * 32 + quad * 8);
                bf16x8 af = __builtin_bit_cast(bf16x8, araw);
                #pragma unroll
                for (int c = 0; c < 2; ++c)
                    acc[c] = __builtin_amdgcn_mfma_f32_16x16x32_bf16(
                        af, __builtin_bit_cast(bf16x8, Bfr[c][ks]), acc[c], 0, 0, 0);
            }
            #pragma unroll
            for (int c = 0; c < 2; ++c)
                #pragma unroll
                for (int r = 0; r < 4; ++r)
                    st[(quad * 4 + r) * 32 + c * 16 + n15] = acc[c][r] + bias[c];
            // 16 rows x 32 cols fp32 = 2 KB: two passes of 64 lanes x 16 B
            #pragma unroll
            for (int p = 0; p < 2; ++p) {
                int fo = p * 256 + lane * 4;
                int r = fo >> 5, cc = fo & 31;
                *(float4*)(out + (size_t)(row0 + r) * 128 + w * 32 + cc) =
                    *(const float4*)(st + fo);
            }
        }
    }
}

// ---------------------------------------------------------------------------
extern "C" void kernel_launch(void* const* d_in, const int* in_sizes, int n_in,
                              void* d_out, int out_size, void* d_ws, size_t ws_size,
                              hipStream_t stream) {
    const float* x     = (const float*)d_in[0];
    const int*   ei    = (const int*)d_in[1];
    const float* W1    = (const float*)d_in[2];
    const float* b1    = (const float*)d_in[3];
    const float* gamma = (const float*)d_in[4];
    const float* beta  = (const float*)d_in[5];
    const float* W2    = (const float*)d_in[6];
    const float* b2    = (const float*)d_in[7];
    const float* eps   = (const float*)d_in[8];
    float* out = (float*)d_out;

    // Workspace: buckets+rowptr adjacent -> single memset.
    // xb doubles as the h buffer for GEMM1 output (dead after k_aggregate).
    float* buckets      = (float*)d_ws;                     // 64*256 floats (64 KB)
    int* rowptr         = (int*)(buckets + NBUCKET * 256);  // N+4 ints
    float* aff          = (float*)(rowptr + N_NODES + 4);   // 256 floats
    unsigned short* Ab  = (unsigned short*)(aff + 256);     // N*128 bf16
    unsigned short* xb  = Ab + (size_t)N_NODES * DIM;       // N*128 bf16 (x, then h)
    unsigned short* Wt1 = xb + (size_t)N_NODES * DIM;       // 16384 bf16
    unsigned short* Wt2 = Wt1 + 16384;                      // 16384 bf16
    int* cursor         = (int*)(Wt2 + 16384);              // N
    int* srcidx         = cursor + N_NODES;                 // E
    int* bsum           = srcidx + NEDGE;                   // 128

    hipMemsetAsync(buckets, 0,
                   NBUCKET * 256 * sizeof(float) + (N_NODES + 4) * sizeof(int), stream);

    k_prep<<<PB_X + 2 * PB_W + PB_CNT, 256, 0, stream>>>(x, W1, W2, ei, xb, Wt1, Wt2, rowptr);
    k_scan1<<<NB_SCAN, 256, 0, stream>>>(rowptr, bsum);
    k_scan_add<<<NB_SCAN, 256, 0, stream>>>(rowptr, bsum, cursor);
    k_fill<<<(NEDGE + 255) / 256, 256, 0, stream>>>(ei, cursor, srcidx);
    k_aggregate<<<(N_NODES * 64) / 256, 256, 0, stream>>>(xb, rowptr, srcidx, eps, Ab);
    k_gemm1<<<GGRID, 256, 0, stream>>>(Ab, xb, Wt1, b1, buckets);   // h -> xb
    k_finalize<<<1, 128, 0, stream>>>(gamma, beta, buckets, aff);
    k_gemm2<<<GGRID, 256, 0, stream>>>(xb, Wt2, aff, b2, out);
}